// Round 7
// baseline (71645.862 us; speedup 1.0000x reference)
//
#include <hip/hip_runtime.h>
#include <stdint.h>

typedef unsigned short u16;
typedef unsigned int   u32;

__device__ __forceinline__ float bf2f(u16 b){ return __uint_as_float(((u32)b) << 16); }
// flag: 0 = source is bf16, 1 = source is f32
__device__ __forceinline__ float ldf(const void* p, size_t i, int flag){
  return flag ? ((const float*)p)[i] : bf2f(((const u16*)p)[i]);
}

// ---------------- sentinel (diagnostic channel, f32 now) ----------------
__global__ void k_sentinelf(float* __restrict__ out, int n, float val){
  int i = blockIdx.x*256 + threadIdx.x;
  if(i < n) out[i] = val;
}

// ---------------- dtype detection + canonicalize ----------------
__global__ void k_detect(const u16* __restrict__ p, int n, int* __restrict__ flag){
  __shared__ int cnt;
  if(threadIdx.x == 0) cnt = 0;
  __syncthreads();
  int c = 0;
  for(int i = threadIdx.x; i < n; i += 256){
    int e = (p[i] >> 7) & 0xFF;
    c += (e >= 112 && e <= 142) ? 1 : 0;
  }
  atomicAdd(&cnt, c);
  __syncthreads();
  if(threadIdx.x == 0) *flag = (cnt >= (n/10)*9) ? 0 : 1;
}
__global__ void k_convf(const void* __restrict__ src, float* __restrict__ dst, int n,
                        const int* __restrict__ flag){
  int i = blockIdx.x*256 + threadIdx.x;
  if(i < n) dst[i] = ldf(src, i, *flag);
}

// ---------------- weight packs (coalesced gemv layouts) ----------------
// WQ[d][k][a]: k<256 -> Wi[d][k][a]; k>=256 -> Wh[d][k-256][a]
__global__ void k_pack_wq(const void* __restrict__ Wi, const void* __restrict__ Wh,
                          float* __restrict__ out, const int* __restrict__ flag){
  int i = blockIdx.x*256 + threadIdx.x;
  if(i >= 2*512*256) return;
  int d = i >> 17, rem = i & 131071;
  int k = rem >> 8, a = rem & 255;
  float v;
  if(k < 256) v = ldf(Wi, ((size_t)d*256 + k)*256 + a, *flag);
  else        v = ldf(Wh, ((size_t)d*256 + (k-256))*256 + a, *flag);
  out[i] = v;
}
// Wc[d][k][j]: j<768 -> Whh[d][j][k]; 768..1536 -> Wih[d][j-768][256+k];
// j>=1536 -> Wih[d][j-1536][k]
__global__ void k_pack_wcf(const void* __restrict__ Whh, const void* __restrict__ Wih,
                           float* __restrict__ out, const int* __restrict__ flag){
  int i = blockIdx.x*256 + threadIdx.x;
  if(i >= 2*256*2304) return;
  int d = i / 589824, rem = i % 589824;
  int k = rem / 2304, j = rem % 2304;
  float v;
  if(j < 768)        v = ldf(Whh, ((size_t)d*768 + j)*256 + k, *flag);
  else if(j < 1536)  v = ldf(Wih, ((size_t)d*768 + (j-768))*512 + 256 + k, *flag);
  else               v = ldf(Wih, ((size_t)d*768 + (j-1536))*512 + k, *flag);
  out[i] = v;
}

// ---------------- f32 tiled GEMM: C[m][n] = sum_k A[m][k]*B[k][n], f32 out --------
__global__ __launch_bounds__(256)
void k_gemm_f32(const float* __restrict__ A, int lda,
                const float* __restrict__ B, int ldb,
                float* __restrict__ C, int N, int K)
{
  __shared__ float As[64][17];
  __shared__ float Bs[16][65];
  const int m0 = blockIdx.x * 64, n0 = blockIdx.y * 64;
  const int tid = threadIdx.x;
  const int arow = tid >> 2, acol = (tid & 3) * 4;
  const int brow = tid >> 4, bcol = (tid & 15) * 4;
  const int ty = tid >> 4, tx = tid & 15;

  float acc[4][4];
  #pragma unroll
  for(int i=0;i<4;++i)
    #pragma unroll
    for(int j=0;j<4;++j) acc[i][j] = 0.f;

  for(int k0 = 0; k0 < K; k0 += 16){
    {
      float4 a4 = *(const float4*)(A + (size_t)(m0 + arow)*lda + k0 + acol);
      As[arow][acol+0] = a4.x; As[arow][acol+1] = a4.y;
      As[arow][acol+2] = a4.z; As[arow][acol+3] = a4.w;
      float4 b4 = *(const float4*)(B + (size_t)(k0 + brow)*ldb + n0 + bcol);
      Bs[brow][bcol+0] = b4.x; Bs[brow][bcol+1] = b4.y;
      Bs[brow][bcol+2] = b4.z; Bs[brow][bcol+3] = b4.w;
    }
    __syncthreads();
    #pragma unroll
    for(int kk = 0; kk < 16; ++kk){
      float ar[4], br[4];
      #pragma unroll
      for(int i=0;i<4;++i) ar[i] = As[ty*4+i][kk];
      #pragma unroll
      for(int j=0;j<4;++j) br[j] = Bs[kk][tx*4+j];
      #pragma unroll
      for(int i=0;i<4;++i)
        #pragma unroll
        for(int j=0;j<4;++j) acc[i][j] = fmaf(ar[i], br[j], acc[i][j]);
    }
    __syncthreads();
  }

  #pragma unroll
  for(int i=0;i<4;++i)
    #pragma unroll
    for(int j=0;j<4;++j)
      C[(size_t)(m0 + ty*4 + i)*N + n0 + tx*4 + j] = acc[i][j];
}

// ---------------- recurrent scan: one WG per (dir, batch); accurate f32 ----------
// Naive-faithful numerics (tanhf, max-subtracted softmax, expf, division),
// packed coalesced weights, f32 ys straight into d_out.
__global__ __launch_bounds__(1024)
void k_scan(const float* __restrict__ P,     // [2][16384][256] f32  mem@Wm
            const float* __restrict__ WQ,    // [2][512][256] f32  (x|h) -> q
            const float* __restrict__ Wc,    // [2][256][2304] f32
            const float* __restrict__ xf,    // [32][512][256] f32
            const float* __restrict__ memf,  // [32][512][256] f32
            const float* __restrict__ vf,    // [2][256] f32
            const float* __restrict__ bihf,  // [2][768] f32
            const float* __restrict__ bhhf,  // [2][768] f32
            float* __restrict__ ys)          // [32][512][512] f32 = d_out
{
  __shared__ float h[256];
  __shared__ float c[256];
  __shared__ float xt[256];
  __shared__ float qn[256];
  __shared__ float sv[512];
  __shared__ float aw[512];
  __shared__ float part[4096];
  __shared__ float ghgi[2304];
  __shared__ float red[16];
  __shared__ float smax_sh, rsum_sh;

  const int tid = threadIdx.x;
  const int p = blockIdx.x, d = p >> 5, b = p & 31;
  const int lane = tid & 63, wave = tid >> 6;
  const int a4 = lane * 4;

  if(tid < 256) h[tid] = 0.f;

  const float va0 = vf[d*256 + a4 + 0];
  const float va1 = vf[d*256 + a4 + 1];
  const float va2 = vf[d*256 + a4 + 2];
  const float va3 = vf[d*256 + a4 + 3];
  float bh0=0.f, bh1=0.f, bh2=0.f, bi0=0.f, bi1=0.f, bi2=0.f;
  if(tid < 256){
    bh0 = bhhf[d*768 + tid];
    bh1 = bhhf[d*768 + 256 + tid];
    bh2 = bhhf[d*768 + 512 + tid];
    bi0 = bihf[d*768 + tid];
    bi1 = bihf[d*768 + 256 + tid];
    bi2 = bihf[d*768 + 512 + tid];
  }

  const float* Pb  = P    + ((size_t)d*16384 + (size_t)b*512) * 256;
  const float* WQd = WQ   + (size_t)d*512*256;
  const float* Wcd = Wc   + (size_t)d*256*2304;
  const float* mb  = memf + (size_t)b*512*256;
  const float* xb  = xf   + (size_t)b*512*256;

  for(int step = 0; step < 512; ++step){
    const int tx = d ? (511 - step) : step;

    if(tid < 256) xt[tid] = xb[(size_t)tx*256 + tid];
    __syncthreads();   // B1: xt + prev h ready

    // ---- Phase Q: q_a = sum_k (x|h)_k WQ[k][a]  (4 k-quarters of 128)
    {
      const int a = tid & 255, kq = tid >> 8;
      const float* wp = WQd + (size_t)(kq*128)*256 + a;
      const float* src = (kq < 2) ? (xt + kq*128) : (h + (kq-2)*128);
      float acc = 0.f;
      #pragma unroll 4
      for(int i=0;i<128;++i) acc = fmaf(src[i], wp[(size_t)i*256], acc);
      part[kq*256 + a] = acc;
    }
    __syncthreads();   // B2
    if(tid < 256) qn[tid] = part[tid] + part[256+tid] + part[512+tid] + part[768+tid];
    __syncthreads();   // B3: q ready

    // ---- Phase A: s_m = sum_a v_a * tanhf(P[m][a] + q_a)
    {
      const float q0 = qn[a4], q1 = qn[a4+1], q2 = qn[a4+2], q3 = qn[a4+3];
      for(int i=0;i<32;++i){
        int m = wave*32 + i;
        float4 p4 = *(const float4*)(Pb + (size_t)m*256 + a4);
        float s = va0*tanhf(p4.x + q0) + va1*tanhf(p4.y + q1)
                + va2*tanhf(p4.z + q2) + va3*tanhf(p4.w + q3);
        #pragma unroll
        for(int off=1; off<64; off<<=1) s += __shfl_xor(s, off, 64);
        if(lane == 0) sv[m] = s;
      }
    }
    __syncthreads();   // B4: scores ready

    // ---- softmax: max-subtracted, expf, true division
    if(tid < 512){
      float mx = sv[tid];
      #pragma unroll
      for(int off=1; off<64; off<<=1) mx = fmaxf(mx, __shfl_xor(mx, off, 64));
      if(lane == 0) red[wave] = mx;
    }
    __syncthreads();
    if(tid == 0){
      float mx = red[0];
      for(int i=1;i<8;++i) mx = fmaxf(mx, red[i]);
      smax_sh = mx;
    }
    __syncthreads();
    if(tid < 512){
      float e = expf(sv[tid] - smax_sh);
      aw[tid] = e;
      #pragma unroll
      for(int off=1; off<64; off<<=1) e += __shfl_xor(e, off, 64);
      if(lane == 0) red[8 + wave] = e;
    }
    __syncthreads();
    if(tid == 0){
      float s = 0.f; for(int i=0;i<8;++i) s += red[8+i];
      rsum_sh = 1.0f / s;
    }
    __syncthreads();   // aw + rsum ready

    // ---- Phase C: c = (sum_m aw_m * mem[m][:]) * rsum   (16 wave partials)
    {
      float c0=0.f,c1=0.f,c2v=0.f,c3=0.f;
      for(int i=0;i<32;++i){
        int m = wave*32 + i;
        float e = aw[m];
        float4 m4 = *(const float4*)(mb + (size_t)m*256 + a4);
        c0  = fmaf(m4.x, e, c0);
        c1  = fmaf(m4.y, e, c1);
        c2v = fmaf(m4.z, e, c2v);
        c3  = fmaf(m4.w, e, c3);
      }
      part[wave*256 + a4    ] = c0;
      part[wave*256 + a4 + 1] = c1;
      part[wave*256 + a4 + 2] = c2v;
      part[wave*256 + a4 + 3] = c3;
    }
    __syncthreads();
    if(tid < 256){
      float cv = 0.f;
      #pragma unroll
      for(int w=0; w<16; ++w) cv += part[w*256 + tid];
      c[tid] = cv * rsum_sh;
    }
    __syncthreads();   // c ready

    // ---- Phase G: 2304 coalesced dots of length 256
    {
      {
        const int j1 = tid;
        const float* wp = Wcd + j1;
        const float* src = (j1 < 768) ? h : c;
        float acc = 0.f;
        #pragma unroll 4
        for(int k=0;k<256;++k) acc = fmaf(src[k], wp[(size_t)k*2304], acc);
        ghgi[j1] = acc;
      }
      {
        const int j2 = 1024 + tid;
        const float* wp = Wcd + j2;
        const float* src = (j2 < 1536) ? c : xt;
        float acc = 0.f;
        #pragma unroll 4
        for(int k=0;k<256;++k) acc = fmaf(src[k], wp[(size_t)k*2304], acc);
        ghgi[j2] = acc;
      }
      if(tid < 256){
        const int j3 = 2048 + tid;
        const float* wp = Wcd + j3;
        float acc = 0.f;
        #pragma unroll 4
        for(int k=0;k<256;++k) acc = fmaf(xt[k], wp[(size_t)k*2304], acc);
        ghgi[j3] = acc;
      }
    }
    __syncthreads();   // gates input ready

    // ---- gates + h update (expf/division, reference-faithful)
    if(tid < 256){
      const int j = tid;
      float hr  = ghgi[j]       + bh0;
      float hz  = ghgi[256 + j] + bh1;
      float hn  = ghgi[512 + j] + bh2;
      float ir  = ghgi[1536 + j]       + ghgi[768 + j]       + bi0;
      float iz  = ghgi[1536 + 256 + j] + ghgi[768 + 256 + j] + bi1;
      float inn = ghgi[1536 + 512 + j] + ghgi[768 + 512 + j] + bi2;
      float r = 1.f/(1.f + expf(-(ir + hr)));
      float z = 1.f/(1.f + expf(-(iz + hz)));
      float n = tanhf(inn + r*hn);
      float hnew = (1.f - z)*n + z*h[j];
      h[j] = hnew;
      ys[((size_t)b*512 + tx)*512 + d*256 + j] = hnew;   // f32 write
    }
    __syncthreads();   // protect h before next Phase Q
  }
}

// ---------------- final gate: out = sigmoid(G) * ys, f32 in-place ----------------
__global__ void k_gate(const float* __restrict__ G, float* __restrict__ ysb, int n4){
  int i = blockIdx.x*256 + threadIdx.x;
  if(i >= n4) return;
  float4 g = ((const float4*)G)[i];
  float4 y = ((const float4*)ysb)[i];
  float4 o;
  o.x = y.x / (1.f + expf(-g.x));
  o.y = y.y / (1.f + expf(-g.y));
  o.z = y.z / (1.f + expf(-g.z));
  o.w = y.w / (1.f + expf(-g.w));
  ((float4*)ysb)[i] = o;
}

// ---------------- host ----------------
extern "C" void kernel_launch(void* const* d_in, const int* in_sizes, int n_in,
                              void* d_out, int out_size, void* d_ws, size_t ws_size,
                              hipStream_t stream)
{
  // robust input mapping by element-count signature
  int iIn=-1, iMem=-1, iW[3]={-1,-1,-1}, nW=0, iV=-1, iWih=-1, iWhh=-1,
      iBih=-1, iBhh=-1, iWg=-1;
  for(int i = 0; i < n_in; ++i){
    switch(in_sizes[i]){
      case 4194304: if(iIn < 0) iIn = i; else if(iMem < 0) iMem = i; break;
      case 131072:  if(nW < 3) iW[nW++] = i; break;
      case 512:     iV = i; break;
      case 786432:  iWih = i; break;
      case 393216:  iWhh = i; break;
      case 1536:    if(iBih < 0) iBih = i; else if(iBhh < 0) iBhh = i; break;
      case 262144:  iWg = i; break;
      default: break;
    }
  }
  bool ok = (iIn>=0 && iMem>=0 && nW==3 && iV>=0 && iWih>=0 && iWhh>=0 &&
             iBih>=0 && iBhh>=0 && iWg>=0);
  if(!ok){
    k_sentinelf<<<(out_size + 255)/256, 256, 0, stream>>>((float*)d_out, out_size, 42.0f);
    return;
  }

  char* ws = (char*)d_ws;
  size_t off = 0;
  auto alloc = [&](size_t bytes)->void*{
    void* pp = ws + off; off += (bytes + 255) & ~(size_t)255; return pp;
  };
  float* cxf   = (float*)alloc(4194304ull*4);     // 16.8 MB (reused by G after scan)
  float* cmemf = (float*)alloc(4194304ull*4);     // 16.8 MB (contiguous with cxf)
  float* P     = (float*)alloc(2ull*16384*256*4); // 33.6 MB
  float* WQ    = (float*)alloc(2ull*512*256*4);   //  1.0 MB
  float* Wc    = (float*)alloc(2ull*256*2304*4);  //  4.7 MB
  float* Wmf   = (float*)alloc(131072ull*4);      //  0.5 MB
  float* Wgf   = (float*)alloc(262144ull*4);      //  1.0 MB
  float* cvf   = (float*)alloc(512ull*4);
  float* bihf  = (float*)alloc(1536ull*4);
  float* bhhf  = (float*)alloc(1536ull*4);
  int*   flag  = (int*)  alloc(256);
  if(off > ws_size){
    k_sentinelf<<<(out_size + 255)/256, 256, 0, stream>>>((float*)d_out, out_size, 43.0f);
    return;
  }

  k_detect<<<1, 256, 0, stream>>>((const u16*)d_in[iIn], 65536, flag);

  auto conv = [&](const void* src, float* dst, int n){
    k_convf<<<(n + 255)/256, 256, 0, stream>>>(src, dst, n, flag);
  };
  conv(d_in[iIn],   cxf,   4194304);
  conv(d_in[iMem],  cmemf, 4194304);
  conv(d_in[iW[0]], Wmf,   131072);
  conv(d_in[iV],    cvf,   512);
  conv(d_in[iBih],  bihf,  1536);
  conv(d_in[iBhh],  bhhf,  1536);
  conv(d_in[iWg],   Wgf,   262144);
  k_pack_wq<<<(2*512*256 + 255)/256, 256, 0, stream>>>(d_in[iW[1]], d_in[iW[2]], WQ, flag);
  k_pack_wcf<<<(2*256*2304 + 255)/256, 256, 0, stream>>>(d_in[iWhh], d_in[iWih], Wc, flag);

  // P = memory @ Wm[d]
  for(int dd = 0; dd < 2; ++dd){
    k_gemm_f32<<<dim3(256, 4), 256, 0, stream>>>(
        cmemf, 256, Wmf + (size_t)dd*65536, 256,
        P + (size_t)dd*16384*256, 256, 256);
  }

  // recurrent scan -> ys (f32) straight into d_out
  k_scan<<<64, 1024, 0, stream>>>(P, WQ, Wc, cxf, cmemf, cvf, bihf, bhhf,
                                  (float*)d_out);

  // G = ys@Wg (f32, into cxf+cmemf space which is free after the scan)
  float* G = cxf;   // needs 33.6 MB: cxf(16.8)+cmemf(16.8) are contiguous
  k_gemm_f32<<<dim3(256, 8), 256, 0, stream>>>(
      (const float*)d_out, 512, Wgf, 512, G, 512, 512);

  // out = sigmoid(G) * ys, in place on d_out (same-index read/write)
  k_gate<<<(8388608/4 + 255)/256, 256, 0, stream>>>(G, (float*)d_out, 8388608/4);
}

// Round 8
// 15649.734 us; speedup vs baseline: 4.5781x; 4.5781x over previous
//
#include <hip/hip_runtime.h>
#include <stdint.h>

typedef unsigned short u16;
typedef unsigned int   u32;
typedef _Float16 half2v __attribute__((ext_vector_type(2)));

#define L2E 1.4426950408889634f
#define TWO_L2E 2.8853900817779268f

__device__ __forceinline__ float bf2f(u16 b){ return __uint_as_float(((u32)b) << 16); }
__device__ __forceinline__ float ldf(const void* p, size_t i, int flag){
  return flag ? ((const float*)p)[i] : bf2f(((const u16*)p)[i]);
}
__device__ __forceinline__ float rcpfast(float x){
#if __has_builtin(__builtin_amdgcn_rcpf)
  return __builtin_amdgcn_rcpf(x);
#else
  return 1.0f / x;
#endif
}
__device__ __forceinline__ float exp2fast(float x){
#if __has_builtin(__builtin_amdgcn_exp2f)
  return __builtin_amdgcn_exp2f(x);
#else
  return exp2f(x);
#endif
}
__device__ __forceinline__ float fdot2f(u32 a, u32 b, float c){
#if __has_builtin(__builtin_amdgcn_fdot2)
  return __builtin_amdgcn_fdot2(__builtin_bit_cast(half2v, a), __builtin_bit_cast(half2v, b), c, false);
#else
  half2v ha = __builtin_bit_cast(half2v, a), hb = __builtin_bit_cast(half2v, b);
  return c + (float)ha[0]*(float)hb[0] + (float)ha[1]*(float)hb[1];
#endif
}
__device__ __forceinline__ u32 pkh2(float lo, float hi){
  half2v h; h[0] = (_Float16)lo; h[1] = (_Float16)hi;
  return __builtin_bit_cast(u32, h);
}

// ---------------- sentinel (f32 diagnostic) ----------------
__global__ void k_sentinelf(float* __restrict__ out, int n, float val){
  int i = blockIdx.x*256 + threadIdx.x;
  if(i < n) out[i] = val;
}

// ---------------- dtype detection + canonicalize ----------------
__global__ void k_detect(const u16* __restrict__ p, int n, int* __restrict__ flag){
  __shared__ int cnt;
  if(threadIdx.x == 0) cnt = 0;
  __syncthreads();
  int c = 0;
  for(int i = threadIdx.x; i < n; i += 256){
    int e = (p[i] >> 7) & 0xFF;
    c += (e >= 112 && e <= 142) ? 1 : 0;
  }
  atomicAdd(&cnt, c);
  __syncthreads();
  if(threadIdx.x == 0) *flag = (cnt >= (n/10)*9) ? 0 : 1;
}
__global__ void k_convf(const void* __restrict__ src, float* __restrict__ dst, int n,
                        const int* __restrict__ flag){
  int i = blockIdx.x*256 + threadIdx.x;
  if(i < n) dst[i] = ldf(src, i, *flag);
}

// ---------------- fp16 packs ----------------
// WQ2[d][k2][a], k2<256 (k=2k2,2k2+1 of combined [x|h] dim):
//   k<256 -> Wi[d][k][a]; k>=256 -> Wh[d][k-256][a]
__global__ void k_pack_wq2(const void* __restrict__ Wi, const void* __restrict__ Wh,
                           u32* __restrict__ out, const int* __restrict__ flag){
  int i = blockIdx.x*256 + threadIdx.x;
  if(i >= 2*256*256) return;
  int d = i >> 16, k2 = (i >> 8) & 255, a = i & 255;
  int k = 2*k2;
  float lo, hi;
  if(k < 256){
    lo = ldf(Wi, ((size_t)d*256 + k    )*256 + a, *flag);
    hi = ldf(Wi, ((size_t)d*256 + k + 1)*256 + a, *flag);
  } else {
    lo = ldf(Wh, ((size_t)d*256 + (k-256)    )*256 + a, *flag);
    hi = ldf(Wh, ((size_t)d*256 + (k-256) + 1)*256 + a, *flag);
  }
  out[i] = pkh2(lo, hi);
}
// Wc2[d][k2][j], k2<128 (k=2k2,2k2+1), j<2304:
//   j<768: Whh[d][j][k]; 768..1536: Wih[d][j-768][256+k]; >=1536: Wih[d][j-1536][k]
__global__ void k_pack_wc2(const void* __restrict__ Whh, const void* __restrict__ Wih,
                           u32* __restrict__ out, const int* __restrict__ flag){
  int i = blockIdx.x*256 + threadIdx.x;
  if(i >= 2*128*2304) return;
  int d = i / (128*2304), r = i % (128*2304);
  int k2 = r / 2304, j = r % 2304;
  int k = 2*k2;
  float lo, hi;
  if(j < 768){
    lo = ldf(Whh, ((size_t)d*768 + j)*256 + k,     *flag);
    hi = ldf(Whh, ((size_t)d*768 + j)*256 + k + 1, *flag);
  } else if(j < 1536){
    lo = ldf(Wih, ((size_t)d*768 + (j-768))*512 + 256 + k,     *flag);
    hi = ldf(Wih, ((size_t)d*768 + (j-768))*512 + 256 + k + 1, *flag);
  } else {
    lo = ldf(Wih, ((size_t)d*768 + (j-1536))*512 + k,     *flag);
    hi = ldf(Wih, ((size_t)d*768 + (j-1536))*512 + k + 1, *flag);
  }
  out[i] = pkh2(lo, hi);
}
// memh2: flat fp16 pair pack of memory
__global__ void k_pack_memh(const void* __restrict__ mem, u32* __restrict__ out, int n2,
                            const int* __restrict__ flag){
  int i = blockIdx.x*256 + threadIdx.x;
  if(i >= n2) return;
  out[i] = pkh2(ldf(mem, 2*(size_t)i, *flag), ldf(mem, 2*(size_t)i + 1, *flag));
}

// ---------------- f32 tiled GEMM: C[m][n] = sum_k A[m][k]*B[k][n] ----------------
// SCALE: multiply output by 2*log2(e) (for pre-scaled P')
template<int SCALE>
__global__ __launch_bounds__(256)
void k_gemm_f32(const float* __restrict__ A, int lda,
                const float* __restrict__ B, int ldb,
                float* __restrict__ C, int N, int K)
{
  __shared__ float As[64][17];
  __shared__ float Bs[16][65];
  const int m0 = blockIdx.x * 64, n0 = blockIdx.y * 64;
  const int tid = threadIdx.x;
  const int arow = tid >> 2, acol = (tid & 3) * 4;
  const int brow = tid >> 4, bcol = (tid & 15) * 4;
  const int ty = tid >> 4, tx = tid & 15;

  float acc[4][4];
  #pragma unroll
  for(int i=0;i<4;++i)
    #pragma unroll
    for(int j=0;j<4;++j) acc[i][j] = 0.f;

  for(int k0 = 0; k0 < K; k0 += 16){
    float4 a4 = *(const float4*)(A + (size_t)(m0 + arow)*lda + k0 + acol);
    As[arow][acol+0] = a4.x; As[arow][acol+1] = a4.y;
    As[arow][acol+2] = a4.z; As[arow][acol+3] = a4.w;
    float4 b4 = *(const float4*)(B + (size_t)(k0 + brow)*ldb + n0 + bcol);
    Bs[brow][bcol+0] = b4.x; Bs[brow][bcol+1] = b4.y;
    Bs[brow][bcol+2] = b4.z; Bs[brow][bcol+3] = b4.w;
    __syncthreads();
    #pragma unroll
    for(int kk = 0; kk < 16; ++kk){
      float ar[4], br[4];
      #pragma unroll
      for(int i=0;i<4;++i) ar[i] = As[ty*4+i][kk];
      #pragma unroll
      for(int j=0;j<4;++j) br[j] = Bs[kk][tx*4+j];
      #pragma unroll
      for(int i=0;i<4;++i)
        #pragma unroll
        for(int j=0;j<4;++j) acc[i][j] = fmaf(ar[i], br[j], acc[i][j]);
    }
    __syncthreads();
  }

  #pragma unroll
  for(int i=0;i<4;++i)
    #pragma unroll
    for(int j=0;j<4;++j){
      float v = acc[i][j];
      if(SCALE) v *= TWO_L2E;
      C[(size_t)(m0 + ty*4 + i)*N + n0 + tx*4 + j] = v;
    }
}

// ---------------- recurrent scan v2: fp16 dots, fused A+C, 8 barriers/step -------
__global__ __launch_bounds__(1024)
void k_scan2(const float* __restrict__ P,     // [2][16384][256] f32, pre-scaled by 2log2e
             const u32* __restrict__ WQ2,    // [2][256][256] fp16 pairs (k-major)
             const u32* __restrict__ Wc2,    // [2][128][2304] fp16 pairs
             const float* __restrict__ xf,   // [32][512][256] f32
             const u32* __restrict__ memh2,  // [32][512][128] fp16 pairs
             const float* __restrict__ vf,   // [2][256]
             const float* __restrict__ bihf, // [2][768]
             const float* __restrict__ bhhf, // [2][768]
             float* __restrict__ ys)         // [32][512][512] f32 = d_out
{
  __shared__ float h[256];
  __shared__ u32 h2[128], c2[128], x2[128];
  __shared__ float qn[256];
  __shared__ __align__(16) float part[4096];
  __shared__ float ghgi[2304];
  __shared__ float expp[16];
  __shared__ float svp_sh;

  const int tid = threadIdx.x;
  const int p = blockIdx.x, d = p >> 5, b = p & 31;
  const int lane = tid & 63, wave = tid >> 6;
  const int a4 = lane * 4;

  const float* Pb  = P     + ((size_t)d*16384 + (size_t)b*512) * 256;
  const u32*  WQd  = WQ2   + (size_t)d*256*256;
  const u32*  Wcd  = Wc2   + (size_t)d*128*2304;
  const u32*  mhb  = memh2 + (size_t)b*512*128;
  const float* xb  = xf    + (size_t)b*512*256;

  // ---- prologue
  if(tid < 256){ h[tid] = 0.f; part[tid] = vf[d*256 + tid]; }
  if(tid < 128) h2[tid] = 0u;
  if(tid >= 128 && tid < 256){
    int t = tid - 128, tx0 = d ? 511 : 0;
    float2 xv = *(const float2*)(xb + (size_t)tx0*256 + 2*t);
    x2[t] = pkh2(xv.x, xv.y);
  }
  const float va0 = vf[d*256 + a4 + 0];
  const float va1 = vf[d*256 + a4 + 1];
  const float va2 = vf[d*256 + a4 + 2];
  const float va3 = vf[d*256 + a4 + 3];
  float bh0=0.f,bh1=0.f,bh2=0.f,bi0=0.f,bi1=0.f,bi2=0.f;
  if(tid < 256){
    bh0 = bhhf[d*768 + tid];       bi0 = bihf[d*768 + tid];
    bh1 = bhhf[d*768 + 256 + tid]; bi1 = bihf[d*768 + 256 + tid];
    bh2 = bhhf[d*768 + 512 + tid]; bi2 = bihf[d*768 + 512 + tid];
  }
  __syncthreads();
  if(tid == 0){ float s=0.f; for(int i=0;i<256;++i) s += part[i]; svp_sh = s * L2E; }
  __syncthreads();   // B1 (of step 0)

  for(int step = 0; step < 512; ++step){
    const int tx = d ? (511 - step) : step;

    // ---- R_Q: q partials via fdot2 (thread = (kq, a), 2 indep accs)
    {
      const int a = tid & 255, kq = tid >> 8;
      const u32* wp = WQd + (size_t)(kq*64)*256 + a;
      const u32* s2 = (kq < 2) ? (x2 + kq*64) : (h2 + (kq-2)*64);
      float q0 = 0.f, q1 = 0.f;
      #pragma unroll 8
      for(int i=0;i<32;++i){
        q0 = fdot2f(wp[(size_t)i*256],        s2[i],      q0);
        q1 = fdot2f(wp[(size_t)(i+32)*256],   s2[i+32],   q1);
      }
      part[kq*256 + a] = q0 + q1;
    }
    __syncthreads();  // B2
    if(tid < 256)
      qn[tid] = (part[tid] + part[256+tid] + part[512+tid] + part[768+tid]) * TWO_L2E;
    __syncthreads();  // B3

    // ---- R_A: fused scores + exp + context partials (wave handles 32 m-rows)
    {
      const float q0 = qn[a4], q1 = qn[a4+1], q2 = qn[a4+2], q3 = qn[a4+3];
      const float svp = svp_sh;
      float esum = 0.f, c0=0.f, c1=0.f, c2v=0.f, c3=0.f;
      #pragma unroll 2
      for(int i=0;i<32;++i){
        const int m = wave*32 + i;
        float4 p4 = *(const float4*)(Pb + (size_t)m*256 + a4);
        float e0 = exp2fast(p4.x + q0);
        float e1 = exp2fast(p4.y + q1);
        float e2 = exp2fast(p4.z + q2);
        float e3 = exp2fast(p4.w + q3);
        float t0 = rcpfast(1.f + e0);
        float t1 = rcpfast(1.f + e1);
        float t2 = rcpfast(1.f + e2);
        float t3 = rcpfast(1.f + e3);
        float u = fmaf(va0, t0, fmaf(va1, t1, fmaf(va2, t2, va3*t3)));
        #pragma unroll
        for(int off=1; off<64; off<<=1) u += __shfl_xor(u, off, 64);
        float es = exp2fast(fmaf(u, -TWO_L2E, svp));   // e^{s_m}, all lanes
        esum += es;
        uint2 mm = *(const uint2*)(mhb + (size_t)m*128 + lane*2);
        half2v ma = __builtin_bit_cast(half2v, mm.x);
        half2v mb2 = __builtin_bit_cast(half2v, mm.y);
        c0  = fmaf((float)ma[0],  es, c0);
        c1  = fmaf((float)ma[1],  es, c1);
        c2v = fmaf((float)mb2[0], es, c2v);
        c3  = fmaf((float)mb2[1], es, c3);
      }
      *(float4*)&part[wave*256 + a4] = make_float4(c0, c1, c2v, c3);
      if(lane == 0) expp[wave] = esum;
    }
    __syncthreads();  // B4

    // ---- R_c: normalize + pack c2 (tid<128 handles 2 columns)
    if(tid < 128){
      float rs = 0.f;
      #pragma unroll
      for(int w=0; w<16; ++w) rs += expp[w];
      rs = rcpfast(rs);
      float cv0 = 0.f, cv1 = 0.f;
      #pragma unroll
      for(int w=0; w<16; ++w){
        cv0 += part[w*256 + 2*tid];
        cv1 += part[w*256 + 2*tid + 1];
      }
      c2[tid] = pkh2(cv0*rs, cv1*rs);
    }
    __syncthreads();  // B5

    // ---- R_G: 2304 fp16 dots of K=256 (4 indep accs each)
    {
      auto dot128 = [&](const u32* wp, const u32* s2)->float{
        float a0=0.f, a1=0.f, a2=0.f, a3=0.f;
        #pragma unroll 4
        for(int k=0;k<32;++k){
          a0 = fdot2f(wp[(size_t)k*2304],       s2[k],     a0);
          a1 = fdot2f(wp[(size_t)(k+32)*2304],  s2[k+32],  a1);
          a2 = fdot2f(wp[(size_t)(k+64)*2304],  s2[k+64],  a2);
          a3 = fdot2f(wp[(size_t)(k+96)*2304],  s2[k+96],  a3);
        }
        return (a0+a1)+(a2+a3);
      };
      ghgi[tid] = dot128(Wcd + tid, (tid < 768) ? h2 : c2);
      {
        int j2 = 1024 + tid;
        ghgi[j2] = dot128(Wcd + j2, (tid < 512) ? c2 : x2);
      }
      if(tid < 256) ghgi[2048 + tid] = dot128(Wcd + 2048 + tid, x2);
    }
    __syncthreads();  // B6

    // ---- R_gate: GRU update
    if(tid < 256){
      const int j = tid;
      float hr  = ghgi[j]       + bh0;
      float hz  = ghgi[256 + j] + bh1;
      float hn  = ghgi[512 + j] + bh2;
      float ir  = ghgi[1536 + j]       + ghgi[768 + j]       + bi0;
      float iz  = ghgi[1536 + 256 + j] + ghgi[768 + 256 + j] + bi1;
      float inn = ghgi[1536 + 512 + j] + ghgi[768 + 512 + j] + bi2;
      float r = rcpfast(1.f + exp2fast(-(ir + hr) * L2E));
      float z = rcpfast(1.f + exp2fast(-(iz + hz) * L2E));
      float narg = inn + r*hn;
      float n = 1.f - 2.f*rcpfast(1.f + exp2fast(narg * TWO_L2E));
      float hnew = (1.f - z)*n + z*h[j];
      h[j] = hnew;
      ys[((size_t)b*512 + tx)*512 + d*256 + j] = hnew;
    }
    __syncthreads();  // B7

    // ---- R_pack: h2 (tid<128), next x2 (tid 128..255)
    if(tid < 128){
      h2[tid] = pkh2(h[2*tid], h[2*tid+1]);
    } else if(tid < 256 && step < 511){
      int t = tid - 128;
      int txn = d ? (511 - (step+1)) : (step+1);
      float2 xv = *(const float2*)(xb + (size_t)txn*256 + 2*t);
      x2[t] = pkh2(xv.x, xv.y);
    }
    __syncthreads();  // B1 (next step)
  }
}

// ---------------- final gate: out = sigmoid(G) * ys, f32 in-place ----------------
__global__ void k_gate(const float* __restrict__ G, float* __restrict__ ysb, int n4){
  int i = blockIdx.x*256 + threadIdx.x;
  if(i >= n4) return;
  float4 g = ((const float4*)G)[i];
  float4 y = ((const float4*)ysb)[i];
  float4 o;
  o.x = y.x * rcpfast(1.f + exp2fast(-g.x * L2E));
  o.y = y.y * rcpfast(1.f + exp2fast(-g.y * L2E));
  o.z = y.z * rcpfast(1.f + exp2fast(-g.z * L2E));
  o.w = y.w * rcpfast(1.f + exp2fast(-g.w * L2E));
  ((float4*)ysb)[i] = o;
}

// ---------------- host ----------------
extern "C" void kernel_launch(void* const* d_in, const int* in_sizes, int n_in,
                              void* d_out, int out_size, void* d_ws, size_t ws_size,
                              hipStream_t stream)
{
  int iIn=-1, iMem=-1, iW[3]={-1,-1,-1}, nW=0, iV=-1, iWih=-1, iWhh=-1,
      iBih=-1, iBhh=-1, iWg=-1;
  for(int i = 0; i < n_in; ++i){
    switch(in_sizes[i]){
      case 4194304: if(iIn < 0) iIn = i; else if(iMem < 0) iMem = i; break;
      case 131072:  if(nW < 3) iW[nW++] = i; break;
      case 512:     iV = i; break;
      case 786432:  iWih = i; break;
      case 393216:  iWhh = i; break;
      case 1536:    if(iBih < 0) iBih = i; else if(iBhh < 0) iBhh = i; break;
      case 262144:  iWg = i; break;
      default: break;
    }
  }
  bool ok = (iIn>=0 && iMem>=0 && nW==3 && iV>=0 && iWih>=0 && iWhh>=0 &&
             iBih>=0 && iBhh>=0 && iWg>=0);
  if(!ok){
    k_sentinelf<<<(out_size + 255)/256, 256, 0, stream>>>((float*)d_out, out_size, 42.0f);
    return;
  }

  char* ws = (char*)d_ws;
  size_t off = 0;
  auto alloc = [&](size_t bytes)->void*{
    void* pp = ws + off; off += (bytes + 255) & ~(size_t)255; return pp;
  };
  float* cxf   = (float*)alloc(4194304ull*4);     // 16.8 MB (G reuses after scan)
  float* cmemf = (float*)alloc(4194304ull*4);     // 16.8 MB (contiguous with cxf)
  float* P     = (float*)alloc(2ull*16384*256*4); // 33.6 MB (pre-scaled)
  u32*   WQ2   = (u32*)  alloc(2ull*256*256*4);   //  0.5 MB
  u32*   Wc2   = (u32*)  alloc(2ull*128*2304*4);  //  2.4 MB
  u32*   memh2 = (u32*)  alloc(32ull*512*128*4);  //  8.4 MB
  float* Wmf   = (float*)alloc(131072ull*4);
  float* Wgf   = (float*)alloc(262144ull*4);
  float* cvf   = (float*)alloc(512ull*4);
  float* bihf  = (float*)alloc(1536ull*4);
  float* bhhf  = (float*)alloc(1536ull*4);
  int*   flag  = (int*)  alloc(256);
  if(off > ws_size){
    k_sentinelf<<<(out_size + 255)/256, 256, 0, stream>>>((float*)d_out, out_size, 43.0f);
    return;
  }

  k_detect<<<1, 256, 0, stream>>>((const u16*)d_in[iIn], 65536, flag);

  auto conv = [&](const void* src, float* dst, int n){
    k_convf<<<(n + 255)/256, 256, 0, stream>>>(src, dst, n, flag);
  };
  conv(d_in[iIn],   cxf,   4194304);
  conv(d_in[iMem],  cmemf, 4194304);
  conv(d_in[iW[0]], Wmf,   131072);
  conv(d_in[iV],    cvf,   512);
  conv(d_in[iBih],  bihf,  1536);
  conv(d_in[iBhh],  bhhf,  1536);
  conv(d_in[iWg],   Wgf,   262144);
  k_pack_wq2<<<(2*256*256 + 255)/256, 256, 0, stream>>>(d_in[iW[1]], d_in[iW[2]], WQ2, flag);
  k_pack_wc2<<<(2*128*2304 + 255)/256, 256, 0, stream>>>(d_in[iWhh], d_in[iWih], Wc2, flag);
  k_pack_memh<<<(2097152 + 255)/256, 256, 0, stream>>>(d_in[iMem], memh2, 2097152, flag);

  // P' = (memory @ Wm[d]) * 2*log2(e)
  for(int dd = 0; dd < 2; ++dd){
    k_gemm_f32<1><<<dim3(256, 4), 256, 0, stream>>>(
        cmemf, 256, Wmf + (size_t)dd*65536, 256,
        P + (size_t)dd*16384*256, 256, 256);
  }

  // recurrent scan -> ys (f32) straight into d_out
  k_scan2<<<64, 1024, 0, stream>>>(P, WQ2, Wc2, cxf, memh2, cvf, bihf, bhhf,
                                   (float*)d_out);

  // G = ys@Wg (into cxf+cmemf space, free after scan)
  float* G = cxf;
  k_gemm_f32<0><<<dim3(256, 8), 256, 0, stream>>>(
      (const float*)d_out, 512, Wgf, 512, G, 512, 512);
  k_gate<<<(8388608/4 + 255)/256, 256, 0, stream>>>(G, (float*)d_out, 8388608/4);
}